// Round 12
// baseline (839.981 us; speedup 1.0000x reference)
//
#include <hip/hip_runtime.h>
#include <hip/hip_bf16.h>

// Problem constants
#define Bq 32
#define Tq 512
#define Dq 768
#define Mq 2048
#define Kq 32
#define Rq 128
#define Hq 1024
#define NROWS (Mq * Kq)   // 65536
#define CH 32768          // rows per chunk (1024 mentions)
#define NCH (NROWS / CH)  // 2

typedef short short8 __attribute__((ext_vector_type(8)));
typedef unsigned short ushort4v __attribute__((ext_vector_type(4)));
typedef float f32x4 __attribute__((ext_vector_type(4)));

__device__ __forceinline__ unsigned short f2bf(float f) {
    union { float f; unsigned u; } v; v.f = f;
    unsigned r = v.u + 0x7FFFu + ((v.u >> 16) & 1u);   // RNE
    return (unsigned short)(r >> 16);
}
__device__ __forceinline__ float bf2f(unsigned short h) {
    union { unsigned u; float f; } v; v.u = ((unsigned)h) << 16;
    return v.f;
}
// gelu(tanh approx) = x * sigmoid(2*0.79788456*(x + 0.044715 x^3))
__device__ __forceinline__ float gelu_f(float x) {
    float u = x * (1.5957691216057308f + 0.07135481622212034f * x * x);
    return x / (1.0f + __expf(-u));
}

// Block-wide reduce of two values (sum). 256 threads = 4 waves.
__device__ __forceinline__ void block_reduce2(float& a, float& b, float* sm) {
    #pragma unroll
    for (int off = 32; off > 0; off >>= 1) {
        a += __shfl_down(a, off, 64);
        b += __shfl_down(b, off, 64);
    }
    int lane = threadIdx.x & 63, wid = threadIdx.x >> 6;
    if (lane == 0) { sm[wid * 2] = a; sm[wid * 2 + 1] = b; }
    __syncthreads();
    if (threadIdx.x == 0) {
        float sa = 0.f, sb = 0.f;
        #pragma unroll
        for (int w = 0; w < 4; ++w) { sa += sm[w * 2]; sb += sm[w * 2 + 1]; }
        sm[0] = sa; sm[1] = sb;
    }
    __syncthreads();
    a = sm[0]; b = sm[1];
    __syncthreads();
}

// ---------------------------------------------------------------------------
// Weight transpose + f32->bf16: Wt[n][k] = bf16(W[k][n])
__global__ __launch_bounds__(256) void wtrans_k(
    const float* __restrict__ W, unsigned short* __restrict__ Wt, int K, int N)
{
    __shared__ unsigned short t[32][33];
    int n0 = blockIdx.x * 32, k0 = blockIdx.y * 32;
    int tx = threadIdx.x & 31, ty = threadIdx.x >> 5;
    #pragma unroll
    for (int i = 0; i < 32; i += 8)
        t[ty + i][tx] = f2bf(W[(long)(k0 + ty + i) * N + n0 + tx]);
    __syncthreads();
    #pragma unroll
    for (int i = 0; i < 32; i += 8)
        Wt[(long)(n0 + ty + i) * K + k0 + tx] = t[tx][ty + i];
}

// ---------------------------------------------------------------------------
// rv (f32) -> rvb (bf16), whole tensor [NROWS][128]
__global__ __launch_bounds__(256) void rv2bf_k(
    const float* __restrict__ rv, unsigned short* __restrict__ rvb)
{
    long i = ((long)blockIdx.x * 256 + threadIdx.x) * 8;
    float4 a = *reinterpret_cast<const float4*>(rv + i);
    float4 b = *reinterpret_cast<const float4*>(rv + i + 4);
    unsigned short v[8] = {f2bf(a.x), f2bf(a.y), f2bf(a.z), f2bf(a.w),
                           f2bf(b.x), f2bf(b.y), f2bf(b.z), f2bf(b.w)};
    *(short8*)(rvb + i) = *(short8*)v;
}

// ---------------------------------------------------------------------------
// Gather concat(start,end) encodings as bf16: cat[m][1536]
__global__ __launch_bounds__(192) void gather_enc_k(
    const float* __restrict__ enc, const int* __restrict__ bpos,
    const int* __restrict__ spos, const int* __restrict__ epos,
    unsigned short* __restrict__ cat)
{
    int m = blockIdx.x;
    int t = threadIdx.x;                 // 0..191
    int b = bpos[m];
    int pos = (t < 96) ? spos[m] : epos[m];
    int off = (t < 96) ? t * 8 : (t - 96) * 8;
    const float4* s = reinterpret_cast<const float4*>(enc + ((long)b * Tq + pos) * Dq + off);
    float4 a = s[0], c = s[1];
    unsigned short v[8] = {f2bf(a.x), f2bf(a.y), f2bf(a.z), f2bf(a.w),
                           f2bf(c.x), f2bf(c.y), f2bf(c.z), f2bf(c.w)};
    *(short8*)(cat + (long)m * 1536 + t * 8) = *(short8*)v;
}

// ---------------------------------------------------------------------------
// 128x128-tile bf16 MFMA GEMM (verified depth-2 counted-vmcnt pipeline).
// Used for the small-M GEMMs (pmv projection, pooled MLP).
template <int ACT, int OUT_BF16, int RESID, int CONCAT>
__global__ __launch_bounds__(256) void mgemm_k(
    const unsigned short* __restrict__ A,
    const unsigned short* __restrict__ Wt,
    const float* __restrict__ bias,
    void* __restrict__ Cout,
    const unsigned short* __restrict__ resid,
    int Kd, int N,
    const unsigned short* __restrict__ pmvb,
    const unsigned short* __restrict__ rvb,
    int row_base)
{
    __shared__ __align__(16) unsigned short AsLin[2][128 * 32];
    __shared__ __align__(16) unsigned short BsLin[2][128 * 32];
    const int tid = threadIdx.x;
    const int w = tid >> 6, lane = tid & 63;
    const int wr = w >> 1, wc = w & 1;
    const int lr = lane & 15, lk = lane >> 4;
    const long r0 = (long)blockIdx.x * 128;
    const int c0 = blockIdx.y * 128;
    const int nt = Kd >> 5;

    auto stage = [&](int buf, int t) {
        const int k0 = t << 5;
        #pragma unroll
        for (int cc = 0; cc < 2; ++cc) {
            int idx = (w * 2 + cc) * 64 + lane;
            int row = idx >> 2, kc = idx & 3;
            int kcol = k0 + kc * 8;
            const unsigned short* ga;
            if (CONCAT) {
                long gr = row_base + r0 + row;
                ga = (kcol < 128) ? pmvb + ((gr >> 5) << 7) + kcol
                                  : rvb + (gr << 7) + (kcol - 128);
            } else {
                ga = A + (r0 + row) * Kd + kcol;
            }
            __builtin_amdgcn_global_load_lds(
                (const __attribute__((address_space(1))) void*)ga,
                (__attribute__((address_space(3))) void*)(&AsLin[buf][(w * 2 + cc) * 512]),
                16, 0, 0);
            const unsigned short* gb = Wt + (long)(c0 + row) * Kd + kcol;
            __builtin_amdgcn_global_load_lds(
                (const __attribute__((address_space(1))) void*)gb,
                (__attribute__((address_space(3))) void*)(&BsLin[buf][(w * 2 + cc) * 512]),
                16, 0, 0);
        }
    };

    f32x4 acc[4][4] = {};

    stage(0, 0);
    if (nt > 1) stage(1, 1);

    for (int t = 0; t < nt; ++t) {
        const int cur = t & 1;
        if (t + 1 < nt) asm volatile("s_waitcnt vmcnt(4)" ::: "memory");
        else            asm volatile("s_waitcnt vmcnt(0)" ::: "memory");
        asm volatile("s_barrier" ::: "memory");

        short8 af[4], bv[4];
        #pragma unroll
        for (int m = 0; m < 4; ++m)
            af[m] = *(const short8*)(&AsLin[cur][(wr * 64 + m * 16 + lr) * 32 + lk * 8]);
        #pragma unroll
        for (int n = 0; n < 4; ++n)
            bv[n] = *(const short8*)(&BsLin[cur][(wc * 64 + n * 16 + lr) * 32 + lk * 8]);

        asm volatile("s_waitcnt lgkmcnt(0)" ::: "memory");
        asm volatile("s_barrier" ::: "memory");

        if (t + 2 < nt) stage(cur, t + 2);

        #pragma unroll
        for (int m = 0; m < 4; ++m)
            #pragma unroll
            for (int n = 0; n < 4; ++n)
                acc[m][n] = __builtin_amdgcn_mfma_f32_16x16x32_bf16(
                    af[m], bv[n], acc[m][n], 0, 0, 0);
    }

    const int cb = c0 + wc * 64;
    #pragma unroll
    for (int n = 0; n < 4; ++n) {
        const int c = cb + n * 16 + lr;
        const float bc = bias[c];
        #pragma unroll
        for (int m = 0; m < 4; ++m) {
            const long r = r0 + wr * 64 + m * 16 + lk * 4;
            #pragma unroll
            for (int j = 0; j < 4; ++j) {
                float v = acc[m][n][j] + bc;
                if (ACT) v = gelu_f(v);
                if (RESID) v += bf2f(resid[(r + j) * N + c]);
                if (OUT_BF16) ((unsigned short*)Cout)[(r + j) * N + c] = f2bf(v);
                else          ((float*)Cout)[(r + j) * N + c] = v;
            }
        }
    }
}

// ---------------------------------------------------------------------------
// 256x256-tile bf16 MFMA GEMM, 8 waves (2Mx4N), BK=32, depth-2 counted-vmcnt
// pipeline + quadrant interleave (Q1 ds_reads under Q0 MFMA) + s_setprio
// around MFMA clusters + XCD-clustered block remap (row-panel sharers on one
// XCD for A-panel L2 reuse). Requires N%256==0, gridDim.x%8==0.
template <int ACT, int OUT_BF16, int RESID, int CONCAT>
__global__ __launch_bounds__(512, 2) void mgemm256_k(
    const unsigned short* __restrict__ A,
    const unsigned short* __restrict__ Wt,
    const float* __restrict__ bias,
    void* __restrict__ Cout,
    const unsigned short* __restrict__ resid,
    int Kd, int N,
    const unsigned short* __restrict__ pmvb,
    const unsigned short* __restrict__ rvb,
    int row_base)
{
    __shared__ __align__(16) unsigned short As[2][256 * 32];
    __shared__ __align__(16) unsigned short Bs[2][256 * 32];
    const int tid = threadIdx.x;
    const int w = tid >> 6, lane = tid & 63;
    const int wr = w >> 2, wc = w & 3;
    const int lr = lane & 15, lk = lane >> 4;

    // XCD-clustered bijective remap: lin%8 ~ XCD (round-robin heuristic);
    // all column-blocks of one A row-panel land on the same XCD.
    const int rows = gridDim.x, cols = gridDim.y;
    const int lin = blockIdx.x + blockIdx.y * rows;
    const int xcd = lin & 7, s = lin >> 3;
    const int rpx = rows >> 3;
    const int bcol = s % cols;
    const int brow = xcd * rpx + s / cols;

    const long r0 = (long)brow * 256;
    const int c0 = bcol * 256;
    const int nt = Kd >> 5;

    auto stage = [&](int buf, int t) {
        const int k0 = t << 5;
        #pragma unroll
        for (int q = 0; q < 2; ++q) {
            // A chunk: 1024 chunks of 16B over [256 rows][32 k]
            int ca = w * 128 + q * 64 + lane;
            int rowa = ca >> 2, kca = ca & 3;
            int kcol = k0 + kca * 8;
            const unsigned short* ga;
            if (CONCAT) {
                long gr = row_base + r0 + rowa;
                ga = (kcol < 128) ? pmvb + ((gr >> 5) << 7) + kcol
                                  : rvb + (gr << 7) + (kcol - 128);
            } else {
                ga = A + (r0 + rowa) * Kd + kcol;
            }
            __builtin_amdgcn_global_load_lds(
                (const __attribute__((address_space(1))) void*)ga,
                (__attribute__((address_space(3))) void*)(&As[buf][(w * 128 + q * 64) * 8]),
                16, 0, 0);
            // B chunk: 1024 chunks of 16B over [256 rows][32 k]
            const unsigned short* gb = Wt + (long)(c0 + rowa) * Kd + kcol;
            __builtin_amdgcn_global_load_lds(
                (const __attribute__((address_space(1))) void*)gb,
                (__attribute__((address_space(3))) void*)(&Bs[buf][(w * 128 + q * 64) * 8]),
                16, 0, 0);
        }
    };

    f32x4 acc[8][4] = {};

    stage(0, 0);
    if (nt > 1) stage(1, 1);

    for (int t = 0; t < nt; ++t) {
        const int cur = t & 1;
        // tile t's 4 loads landed (tile t+1's 4 may remain in flight)
        if (t + 1 < nt) asm volatile("s_waitcnt vmcnt(4)" ::: "memory");
        else            asm volatile("s_waitcnt vmcnt(0)" ::: "memory");
        asm volatile("s_barrier" ::: "memory");

        short8 af0[4], af1[4], bv[4];
        // Q0 fragments: m 0..3 + all B
        #pragma unroll
        for (int m = 0; m < 4; ++m)
            af0[m] = *(const short8*)(&As[cur][(wr * 128 + m * 16 + lr) * 32 + lk * 8]);
        #pragma unroll
        for (int n = 0; n < 4; ++n)
            bv[n] = *(const short8*)(&Bs[cur][(wc * 64 + n * 16 + lr) * 32 + lk * 8]);
        asm volatile("s_waitcnt lgkmcnt(0)" ::: "memory");

        // Q1 A-fragment reads issue now; latency hides under Q0's MFMA burst
        #pragma unroll
        for (int m = 0; m < 4; ++m)
            af1[m] = *(const short8*)(&As[cur][(wr * 128 + (m + 4) * 16 + lr) * 32 + lk * 8]);
        __builtin_amdgcn_sched_barrier(0);   // pin Q1 issue before Q0 MFMA

        __builtin_amdgcn_s_setprio(1);
        #pragma unroll
        for (int m = 0; m < 4; ++m)
            #pragma unroll
            for (int n = 0; n < 4; ++n)
                acc[m][n] = __builtin_amdgcn_mfma_f32_16x16x32_bf16(
                    af0[m], bv[n], acc[m][n], 0, 0, 0);
        __builtin_amdgcn_s_setprio(0);

        asm volatile("s_waitcnt lgkmcnt(0)" ::: "memory");  // all my reads retired
        asm volatile("s_barrier" ::: "memory");             // buffer cur free chip-wide

        if (t + 2 < nt) stage(cur, t + 2);   // into freed buffer, under Q1 MFMA

        __builtin_amdgcn_s_setprio(1);
        #pragma unroll
        for (int m = 0; m < 4; ++m)
            #pragma unroll
            for (int n = 0; n < 4; ++n)
                acc[m + 4][n] = __builtin_amdgcn_mfma_f32_16x16x32_bf16(
                    af1[m], bv[n], acc[m + 4][n], 0, 0, 0);
        __builtin_amdgcn_s_setprio(0);
    }

    // epilogue: C/D layout col=lane&15, row=(lane>>4)*4+reg  [m89/m91 verified]
    const int cb = c0 + wc * 64;
    #pragma unroll
    for (int n = 0; n < 4; ++n) {
        const int c = cb + n * 16 + lr;
        const float bc = bias[c];
        #pragma unroll
        for (int m = 0; m < 8; ++m) {
            const long r = r0 + wr * 128 + m * 16 + lk * 4;
            #pragma unroll
            for (int j = 0; j < 4; ++j) {
                float v = acc[m][n][j] + bc;
                if (ACT) v = gelu_f(v);
                if (RESID) v += bf2f(resid[(r + j) * N + c]);
                if (OUT_BF16) ((unsigned short*)Cout)[(r + j) * N + c] = f2bf(v);
                else          ((float*)Cout)[(r + j) * N + c] = v;
            }
        }
    }
}

// ---------------------------------------------------------------------------
// Stage A of LN+pool: each block handles 8 of a mention's 32 rows (1 row/wave),
// LN (ac_ln) + score-weight, writes partial sums. grid = (CH/32)*4.
__global__ __launch_bounds__(512) void ln_pool_part_k(
    const unsigned short* __restrict__ cvb, const float* __restrict__ scores,
    const float* __restrict__ ln_s, const float* __restrict__ ln_b,
    float* __restrict__ partial,   // [CH/32][4][768]
    int mbase)
{
    __shared__ float part[8][768];
    int lm = blockIdx.x >> 2, ks = blockIdx.x & 3;
    int gm = mbase + lm;
    int tid = threadIdx.x, lane = tid & 63, wid = tid >> 6;
    int k = ks * 8 + wid;
    const unsigned short* row = cvb + ((long)lm * 32 + k) * Dq;

    float v[12], gs[12], gb[12];
    float s = 0.f, ss = 0.f;
    #pragma unroll
    for (int j = 0; j < 3; ++j) {
        int col = j * 256 + lane * 4;
        ushort4v u = *(const ushort4v*)(row + col);
        float4 g = *reinterpret_cast<const float4*>(ln_s + col);
        float4 h = *reinterpret_cast<const float4*>(ln_b + col);
        #pragma unroll
        for (int t = 0; t < 4; ++t) {
            float x = bf2f(u[t]);
            v[j * 4 + t] = x;
            s += x; ss += x * x;
        }
        gs[j * 4 + 0] = g.x; gs[j * 4 + 1] = g.y; gs[j * 4 + 2] = g.z; gs[j * 4 + 3] = g.w;
        gb[j * 4 + 0] = h.x; gb[j * 4 + 1] = h.y; gb[j * 4 + 2] = h.z; gb[j * 4 + 3] = h.w;
    }
    #pragma unroll
    for (int off = 32; off > 0; off >>= 1) {
        s  += __shfl_xor(s, off, 64);
        ss += __shfl_xor(ss, off, 64);
    }
    float mu = s * (1.0f / Dq);
    float var = ss * (1.0f / Dq) - mu * mu;
    float rstd = rsqrtf(var + 1e-12f);
    float sc = scores[gm * 32 + k];
    #pragma unroll
    for (int j = 0; j < 3; ++j) {
        int col = j * 256 + lane * 4;
        #pragma unroll
        for (int t = 0; t < 4; ++t)
            part[wid][col + t] = sc * ((v[j * 4 + t] - mu) * rstd * gs[j * 4 + t] + gb[j * 4 + t]);
    }
    __syncthreads();
    for (int d = tid; d < Dq; d += 512) {
        float acc = 0.f;
        #pragma unroll
        for (int w = 0; w < 8; ++w) acc += part[w][d];
        partial[((long)lm * 4 + ks) * Dq + d] = acc;
    }
}

// Stage B: pooled[m] = sum of 4 partials. grid = CH/32.
__global__ __launch_bounds__(256) void ln_pool_comb_k(
    const float* __restrict__ partial, float* __restrict__ pooledf,
    unsigned short* __restrict__ pooledb, int mbase)
{
    int lm = blockIdx.x, gm = mbase + lm;
    int tid = threadIdx.x;
    for (int d = tid; d < Dq; d += 256) {
        const float* p = partial + (long)lm * 4 * Dq + d;
        float s = p[0] + p[Dq] + p[2 * Dq] + p[3 * Dq];
        pooledf[(long)gm * Dq + d] = s;
        pooledb[(long)gm * Dq + d] = f2bf(s);
    }
}

// ---------------------------------------------------------------------------
// Per-mention: y = LN(pu + pooled; pl_ln) * mask; atomicAdd into out[(b,s)] row.
__global__ __launch_bounds__(256) void ln_mask_scatter_k(
    const float* __restrict__ pu, const float* __restrict__ pooled,
    const float* __restrict__ ln_s, const float* __restrict__ ln_b,
    const float* __restrict__ mask,
    const int* __restrict__ bpos, const int* __restrict__ spos,
    float* __restrict__ out)
{
    __shared__ float sm[8];
    int m = blockIdx.x;
    int tid = threadIdx.x;
    float v[3];
    float s = 0.f, ss = 0.f;
    #pragma unroll
    for (int j = 0; j < 3; ++j) {
        int d = tid + j * 256;
        v[j] = pu[(long)m * Dq + d] + pooled[(long)m * Dq + d];
        s += v[j]; ss += v[j] * v[j];
    }
    block_reduce2(s, ss, sm);
    float mu = s * (1.0f / Dq);
    float var = ss * (1.0f / Dq) - mu * mu;
    float rstd = rsqrtf(var + 1e-12f);
    float mk = mask[m];
    long orow = ((long)bpos[m] * Tq + spos[m]) * Dq;
    #pragma unroll
    for (int j = 0; j < 3; ++j) {
        int d = tid + j * 256;
        float y = ((v[j] - mu) * rstd * ln_s[d] + ln_b[d]) * mk;
        atomicAdd(&out[orow + d], y);
    }
}

// ---------------------------------------------------------------------------
// Final in-place LN over each [768] row of out.
__global__ __launch_bounds__(256) void final_ln_k(
    float* __restrict__ out, const float* __restrict__ ln_s,
    const float* __restrict__ ln_b)
{
    __shared__ float sm[8];
    int tid = threadIdx.x;
    float* row = out + (long)blockIdx.x * Dq;
    float v[3];
    float s = 0.f, ss = 0.f;
    #pragma unroll
    for (int j = 0; j < 3; ++j) {
        v[j] = row[tid + j * 256];
        s += v[j]; ss += v[j] * v[j];
    }
    block_reduce2(s, ss, sm);
    float mu = s * (1.0f / Dq);
    float var = ss * (1.0f / Dq) - mu * mu;
    float rstd = rsqrtf(var + 1e-12f);
    #pragma unroll
    for (int j = 0; j < 3; ++j) {
        int d = tid + j * 256;
        row[d] = (v[j] - mu) * rstd * ln_s[d] + ln_b[d];
    }
}

// ---------------------------------------------------------------------------
extern "C" void kernel_launch(void* const* d_in, const int* in_sizes, int n_in,
                              void* d_out, int out_size, void* d_ws, size_t ws_size,
                              hipStream_t stream) {
    const float* enc    = (const float*)d_in[0];
    const float* rv     = (const float*)d_in[1];
    const float* scores = (const float*)d_in[2];
    const int*   bpos   = (const int*)d_in[3];
    const int*   spos   = (const int*)d_in[4];
    const int*   epos   = (const int*)d_in[5];
    const float* mask   = (const float*)d_in[6];
    const float* vp_w   = (const float*)d_in[7];
    const float* vp_b   = (const float*)d_in[8];
    const float* cm_w   = (const float*)d_in[9];
    const float* cm_b   = (const float*)d_in[10];
    const float* cd_w   = (const float*)d_in[11];
    const float* cd_b   = (const float*)d_in[12];
    const float* ac_w1  = (const float*)d_in[13];
    const float* ac_b1  = (const float*)d_in[14];
    const float* ac_w2  = (const float*)d_in[15];
    const float* ac_b2  = (const float*)d_in[16];
    const float* ac_ln_s = (const float*)d_in[17];
    const float* ac_ln_b = (const float*)d_in[18];
    const float* pl_w1  = (const float*)d_in[19];
    const float* pl_b1  = (const float*)d_in[20];
    const float* pl_w2  = (const float*)d_in[21];
    const float* pl_b2  = (const float*)d_in[22];
    const float* pl_ln_s = (const float*)d_in[23];
    const float* pl_ln_b = (const float*)d_in[24];
    const float* ln_s   = (const float*)d_in[25];
    const float* ln_b   = (const float*)d_in[26];
    float* out = (float*)d_out;

    // workspace layout (bytes), ~224 MB of the confirmed 256 MiB
    char* wsb = (char*)d_ws;
    unsigned short* wt_cm = (unsigned short*)wsb; wsb += (size_t)1024 * 256 * 2;
    unsigned short* wt_cd = (unsigned short*)wsb; wsb += (size_t)768 * 1024 * 2;
    unsigned short* wt_a1 = (unsigned short*)wsb; wsb += (size_t)1024 * 768 * 2;
    unsigned short* wt_a2 = (unsigned short*)wsb; wsb += (size_t)768 * 1024 * 2;
    unsigned short* wt_p1 = (unsigned short*)wsb; wsb += (size_t)1024 * 768 * 2;
    unsigned short* wt_p2 = (unsigned short*)wsb; wsb += (size_t)768 * 1024 * 2;
    unsigned short* wt_vp = (unsigned short*)wsb; wsb += (size_t)128 * 1536 * 2;
    unsigned short* pmvb  = (unsigned short*)wsb; wsb += (size_t)Mq * Rq * 2;
    unsigned short* rvb   = (unsigned short*)wsb; wsb += (size_t)NROWS * Rq * 2;
    unsigned short* catenc = (unsigned short*)wsb; wsb += (size_t)Mq * 1536 * 2;
    unsigned short* hb    = (unsigned short*)wsb; wsb += (size_t)CH * Hq * 2;
    unsigned short* tb    = (unsigned short*)wsb; wsb += (size_t)CH * Dq * 2;
    unsigned short* cvb   = (unsigned short*)wsb; wsb += (size_t)CH * Dq * 2;
    float* partial = (float*)wsb; wsb += (size_t)(CH / Kq) * 4 * Dq * 4;
    float* pooledf = (float*)wsb; wsb += (size_t)Mq * Dq * 4;
    unsigned short* pooledb = (unsigned short*)wsb; wsb += (size_t)Mq * Dq * 2;
    float* puf     = (float*)wsb; wsb += (size_t)Mq * Dq * 4;

    // out = encoded_input (base for scatter-add)
    hipMemcpyAsync(out, enc, (size_t)Bq * Tq * Dq * sizeof(float),
                   hipMemcpyDeviceToDevice, stream);

    // weights -> bf16 transposed [N][K]; rv -> bf16
    wtrans_k<<<dim3(1024 / 32, 256 / 32), 256, 0, stream>>>(cm_w, wt_cm, 256, 1024);
    wtrans_k<<<dim3(768 / 32, 1024 / 32), 256, 0, stream>>>(cd_w, wt_cd, 1024, 768);
    wtrans_k<<<dim3(1024 / 32, 768 / 32), 256, 0, stream>>>(ac_w1, wt_a1, 768, 1024);
    wtrans_k<<<dim3(768 / 32, 1024 / 32), 256, 0, stream>>>(ac_w2, wt_a2, 1024, 768);
    wtrans_k<<<dim3(1024 / 32, 768 / 32), 256, 0, stream>>>(pl_w1, wt_p1, 768, 1024);
    wtrans_k<<<dim3(768 / 32, 1024 / 32), 256, 0, stream>>>(pl_w2, wt_p2, 1024, 768);
    wtrans_k<<<dim3(128 / 32, 1536 / 32), 256, 0, stream>>>(vp_w, wt_vp, 1536, 128);
    rv2bf_k<<<(NROWS * Rq) / (256 * 8), 256, 0, stream>>>(rv, rvb);

    // pmv = concat(start,end) @ vp_w + vp_b  as bf16 MFMA GEMM (128^2 kernel)
    gather_enc_k<<<Mq, 192, 0, stream>>>(enc, bpos, spos, epos, catenc);
    mgemm_k<0, 1, 0, 0><<<dim3(Mq / 128, 1), 256, 0, stream>>>(
        catenc, wt_vp, vp_b, pmvb, nullptr, 1536, Rq, nullptr, nullptr, 0);

    for (int c = 0; c < NCH; ++c) {
        int row_base = c * CH;
        int mbase = c * (CH / Kq);
        // h1 = gelu(concat(pmv,rv) @ cm_w + cm_b)   [CH,1024] bf16 (concat fused)
        mgemm256_k<1, 1, 0, 1><<<dim3(CH / 256, Hq / 256), 512, 0, stream>>>(
            nullptr, wt_cm, cm_b, hb, nullptr, 2 * Rq, Hq, pmvb, rvb, row_base);
        // t = h1 @ cd_w + cd_b                      [CH,768] bf16 (3 col-blocks)
        mgemm256_k<0, 1, 0, 0><<<dim3(CH / 256, Dq / 256), 512, 0, stream>>>(
            hb, wt_cd, cd_b, tb, nullptr, Hq, Dq, nullptr, nullptr, 0);
        // h2 = gelu(t @ ac_w1 + ac_b1)              [CH,1024] bf16
        mgemm256_k<1, 1, 0, 0><<<dim3(CH / 256, Hq / 256), 512, 0, stream>>>(
            tb, wt_a1, ac_b1, hb, nullptr, Dq, Hq, nullptr, nullptr, 0);
        // cv = h2 @ ac_w2 + ac_b2 + t               [CH,768] bf16
        mgemm256_k<0, 1, 1, 0><<<dim3(CH / 256, Dq / 256), 512, 0, stream>>>(
            hb, wt_a2, ac_b2, cvb, tb, Hq, Dq, nullptr, nullptr, 0);
        // LN + score-weighted pool (split-k over 4 blocks/mention, then combine)
        ln_pool_part_k<<<(CH / Kq) * 4, 512, 0, stream>>>(
            cvb, scores, ac_ln_s, ac_ln_b, partial, mbase);
        ln_pool_comb_k<<<CH / Kq, 256, 0, stream>>>(partial, pooledf, pooledb, mbase);
    }

    // pooled MLP (M=2048 -> 128^2 kernel)
    mgemm_k<1, 1, 0, 0><<<dim3(Mq / 128, Hq / 128), 256, 0, stream>>>(
        pooledb, wt_p1, pl_b1, hb, nullptr, Dq, Hq, nullptr, nullptr, 0);
    mgemm_k<0, 0, 0, 0><<<dim3(Mq / 128, Dq / 128), 256, 0, stream>>>(
        hb, wt_p2, pl_b2, puf, nullptr, Hq, Dq, nullptr, nullptr, 0);

    // LN(pu + pooled) * mask, scatter-add into out
    ln_mask_scatter_k<<<Mq, 256, 0, stream>>>(puf, pooledf, pl_ln_s, pl_ln_b,
                                              mask, bpos, spos, out);

    // final LN over every row of out
    final_ln_k<<<Bq * Tq, 256, 0, stream>>>(out, ln_s, ln_b);
}

// Round 13
// 714.456 us; speedup vs baseline: 1.1757x; 1.1757x over previous
//
#include <hip/hip_runtime.h>
#include <hip/hip_bf16.h>

// Problem constants
#define Bq 32
#define Tq 512
#define Dq 768
#define Mq 2048
#define Kq 32
#define Rq 128
#define Hq 1024
#define NROWS (Mq * Kq)   // 65536
#define CH 32768          // rows per chunk (1024 mentions)
#define NCH (NROWS / CH)  // 2

typedef short short8 __attribute__((ext_vector_type(8)));
typedef unsigned short ushort4v __attribute__((ext_vector_type(4)));
typedef float f32x4 __attribute__((ext_vector_type(4)));

__device__ __forceinline__ unsigned short f2bf(float f) {
    union { float f; unsigned u; } v; v.f = f;
    unsigned r = v.u + 0x7FFFu + ((v.u >> 16) & 1u);   // RNE
    return (unsigned short)(r >> 16);
}
__device__ __forceinline__ float bf2f(unsigned short h) {
    union { unsigned u; float f; } v; v.u = ((unsigned)h) << 16;
    return v.f;
}
// gelu(tanh approx) = x * sigmoid(2*0.79788456*(x + 0.044715 x^3))
__device__ __forceinline__ float gelu_f(float x) {
    float u = x * (1.5957691216057308f + 0.07135481622212034f * x * x);
    return x / (1.0f + __expf(-u));
}

// Block-wide reduce of two values (sum). 256 threads = 4 waves.
__device__ __forceinline__ void block_reduce2(float& a, float& b, float* sm) {
    #pragma unroll
    for (int off = 32; off > 0; off >>= 1) {
        a += __shfl_down(a, off, 64);
        b += __shfl_down(b, off, 64);
    }
    int lane = threadIdx.x & 63, wid = threadIdx.x >> 6;
    if (lane == 0) { sm[wid * 2] = a; sm[wid * 2 + 1] = b; }
    __syncthreads();
    if (threadIdx.x == 0) {
        float sa = 0.f, sb = 0.f;
        #pragma unroll
        for (int w = 0; w < 4; ++w) { sa += sm[w * 2]; sb += sm[w * 2 + 1]; }
        sm[0] = sa; sm[1] = sb;
    }
    __syncthreads();
    a = sm[0]; b = sm[1];
    __syncthreads();
}

// ---------------------------------------------------------------------------
// Weight transpose + f32->bf16: Wt[n][k] = bf16(W[k][n])
__global__ __launch_bounds__(256) void wtrans_k(
    const float* __restrict__ W, unsigned short* __restrict__ Wt, int K, int N)
{
    __shared__ unsigned short t[32][33];
    int n0 = blockIdx.x * 32, k0 = blockIdx.y * 32;
    int tx = threadIdx.x & 31, ty = threadIdx.x >> 5;
    #pragma unroll
    for (int i = 0; i < 32; i += 8)
        t[ty + i][tx] = f2bf(W[(long)(k0 + ty + i) * N + n0 + tx]);
    __syncthreads();
    #pragma unroll
    for (int i = 0; i < 32; i += 8)
        Wt[(long)(n0 + ty + i) * K + k0 + tx] = t[tx][ty + i];
}

// ---------------------------------------------------------------------------
// rv (f32) -> rvb (bf16), whole tensor [NROWS][128]
__global__ __launch_bounds__(256) void rv2bf_k(
    const float* __restrict__ rv, unsigned short* __restrict__ rvb)
{
    long i = ((long)blockIdx.x * 256 + threadIdx.x) * 8;
    float4 a = *reinterpret_cast<const float4*>(rv + i);
    float4 b = *reinterpret_cast<const float4*>(rv + i + 4);
    unsigned short v[8] = {f2bf(a.x), f2bf(a.y), f2bf(a.z), f2bf(a.w),
                           f2bf(b.x), f2bf(b.y), f2bf(b.z), f2bf(b.w)};
    *(short8*)(rvb + i) = *(short8*)v;
}

// ---------------------------------------------------------------------------
// Gather concat(start,end) encodings as bf16: cat[m][1536]
__global__ __launch_bounds__(192) void gather_enc_k(
    const float* __restrict__ enc, const int* __restrict__ bpos,
    const int* __restrict__ spos, const int* __restrict__ epos,
    unsigned short* __restrict__ cat)
{
    int m = blockIdx.x;
    int t = threadIdx.x;                 // 0..191
    int b = bpos[m];
    int pos = (t < 96) ? spos[m] : epos[m];
    int off = (t < 96) ? t * 8 : (t - 96) * 8;
    const float4* s = reinterpret_cast<const float4*>(enc + ((long)b * Tq + pos) * Dq + off);
    float4 a = s[0], c = s[1];
    unsigned short v[8] = {f2bf(a.x), f2bf(a.y), f2bf(a.z), f2bf(a.w),
                           f2bf(c.x), f2bf(c.y), f2bf(c.z), f2bf(c.w)};
    *(short8*)(cat + (long)m * 1536 + t * 8) = *(short8*)v;
}

// ---------------------------------------------------------------------------
// 128x128-tile bf16 MFMA GEMM (verified depth-2 counted-vmcnt pipeline).
// Used for the small-M GEMMs (pmv projection, pooled MLP).
template <int ACT, int OUT_BF16, int RESID, int CONCAT>
__global__ __launch_bounds__(256) void mgemm_k(
    const unsigned short* __restrict__ A,
    const unsigned short* __restrict__ Wt,
    const float* __restrict__ bias,
    void* __restrict__ Cout,
    const unsigned short* __restrict__ resid,
    int Kd, int N,
    const unsigned short* __restrict__ pmvb,
    const unsigned short* __restrict__ rvb,
    int row_base)
{
    __shared__ __align__(16) unsigned short AsLin[2][128 * 32];
    __shared__ __align__(16) unsigned short BsLin[2][128 * 32];
    const int tid = threadIdx.x;
    const int w = tid >> 6, lane = tid & 63;
    const int wr = w >> 1, wc = w & 1;
    const int lr = lane & 15, lk = lane >> 4;
    const long r0 = (long)blockIdx.x * 128;
    const int c0 = blockIdx.y * 128;
    const int nt = Kd >> 5;

    auto stage = [&](int buf, int t) {
        const int k0 = t << 5;
        #pragma unroll
        for (int cc = 0; cc < 2; ++cc) {
            int idx = (w * 2 + cc) * 64 + lane;
            int row = idx >> 2, kc = idx & 3;
            int kcol = k0 + kc * 8;
            const unsigned short* ga;
            if (CONCAT) {
                long gr = row_base + r0 + row;
                ga = (kcol < 128) ? pmvb + ((gr >> 5) << 7) + kcol
                                  : rvb + (gr << 7) + (kcol - 128);
            } else {
                ga = A + (r0 + row) * Kd + kcol;
            }
            __builtin_amdgcn_global_load_lds(
                (const __attribute__((address_space(1))) void*)ga,
                (__attribute__((address_space(3))) void*)(&AsLin[buf][(w * 2 + cc) * 512]),
                16, 0, 0);
            const unsigned short* gb = Wt + (long)(c0 + row) * Kd + kcol;
            __builtin_amdgcn_global_load_lds(
                (const __attribute__((address_space(1))) void*)gb,
                (__attribute__((address_space(3))) void*)(&BsLin[buf][(w * 2 + cc) * 512]),
                16, 0, 0);
        }
    };

    f32x4 acc[4][4] = {};

    stage(0, 0);
    if (nt > 1) stage(1, 1);

    for (int t = 0; t < nt; ++t) {
        const int cur = t & 1;
        if (t + 1 < nt) asm volatile("s_waitcnt vmcnt(4)" ::: "memory");
        else            asm volatile("s_waitcnt vmcnt(0)" ::: "memory");
        asm volatile("s_barrier" ::: "memory");

        short8 af[4], bv[4];
        #pragma unroll
        for (int m = 0; m < 4; ++m)
            af[m] = *(const short8*)(&AsLin[cur][(wr * 64 + m * 16 + lr) * 32 + lk * 8]);
        #pragma unroll
        for (int n = 0; n < 4; ++n)
            bv[n] = *(const short8*)(&BsLin[cur][(wc * 64 + n * 16 + lr) * 32 + lk * 8]);

        asm volatile("s_waitcnt lgkmcnt(0)" ::: "memory");
        asm volatile("s_barrier" ::: "memory");

        if (t + 2 < nt) stage(cur, t + 2);

        #pragma unroll
        for (int m = 0; m < 4; ++m)
            #pragma unroll
            for (int n = 0; n < 4; ++n)
                acc[m][n] = __builtin_amdgcn_mfma_f32_16x16x32_bf16(
                    af[m], bv[n], acc[m][n], 0, 0, 0);
    }

    const int cb = c0 + wc * 64;
    #pragma unroll
    for (int n = 0; n < 4; ++n) {
        const int c = cb + n * 16 + lr;
        const float bc = bias[c];
        #pragma unroll
        for (int m = 0; m < 4; ++m) {
            const long r = r0 + wr * 64 + m * 16 + lk * 4;
            #pragma unroll
            for (int j = 0; j < 4; ++j) {
                float v = acc[m][n][j] + bc;
                if (ACT) v = gelu_f(v);
                if (RESID) v += bf2f(resid[(r + j) * N + c]);
                if (OUT_BF16) ((unsigned short*)Cout)[(r + j) * N + c] = f2bf(v);
                else          ((float*)Cout)[(r + j) * N + c] = v;
            }
        }
    }
}

// ---------------------------------------------------------------------------
// 8-phase-style 256xBN bf16 MFMA GEMM. BK=64, 8 waves (2M x 4N), 512 thr.
// Per K-tile: 4 phases (mh x kk quadrants), 16*NF/4 MFMA each, per-phase
// {ds_read frags, stage next-tile unit, barrier, lgkmcnt(0), setprio(1),
// MFMA, setprio(0), barrier}. 2 LDS buffers (A 64KB + B 16*NF KB).
// T2: slot ^= (row&7) XOR swizzle, applied to BOTH the pre-swizzled global
// source (rule #21) and the frag reads -> conflict-free at 128B rows.
// Staging: prologue stages tiles 0,1; tile t>=1 stages t+1 (A in P1, B in P2)
// into the buffer freed at (t-1).P4; vmcnt(0) at P4-end waits only tile t+1
// (nothing further in flight with 2 buffers -> provably race-free).
// NF=4 -> BN=256; NF=3 -> BN=192. Requires gridDim.x % 8 == 0.
template <int ACT, int OUT_BF16, int RESID, int CONCAT, int NF>
__global__ __launch_bounds__(512, 1) void mg8_k(
    const unsigned short* __restrict__ A,
    const unsigned short* __restrict__ Wt,
    const float* __restrict__ bias,
    void* __restrict__ Cout,
    const unsigned short* __restrict__ resid,
    int Kd, int N,
    const unsigned short* __restrict__ pmvb,
    const unsigned short* __restrict__ rvb,
    int row_base)
{
    __shared__ __align__(16) unsigned short As[2][256 * 64];
    __shared__ __align__(16) unsigned short Bs[2][NF * 64 * 64];
    const int tid = threadIdx.x;
    const int w = tid >> 6, lane = tid & 63;
    const int wr = w >> 2, wc = w & 3;
    const int lr = lane & 15, lk = lane >> 4;

    // XCD-clustered bijective remap (row-panel sharers on one XCD)
    const int rows = gridDim.x, cols = gridDim.y;
    const int lin = blockIdx.x + blockIdx.y * rows;
    const int xcd = lin & 7, sq = lin >> 3;
    const int rpx = rows >> 3;
    const int bcol = sq % cols;
    const int brow = xcd * rpx + sq / cols;

    const long r0 = (long)brow * 256;
    const int c0 = bcol * (NF * 64);
    const int nt = Kd >> 6;
    const int swz = (lr & 7) << 3;      // frag-read XOR, in shorts (16B units)

    // stage full A K-tile (256 rows x 64 k = 32KB): 4 x gload_lds(16B)/thread
    auto stageA = [&](int buf, int t) {
        #pragma unroll
        for (int q = 0; q < 4; ++q) {
            int idx = q * 512 + tid;            // 0..2047
            int row = idx >> 3;                 // 0..255
            int slot = (idx & 7) ^ (row & 7);   // pre-swizzled global slot
            int gk = (t << 6) + slot * 8;
            const unsigned short* ga;
            if (CONCAT) {
                long gr = row_base + r0 + row;
                ga = (gk < 128) ? pmvb + ((gr >> 5) << 7) + gk
                                : rvb + (gr << 7) + (gk - 128);
            } else {
                ga = A + (r0 + row) * Kd + gk;
            }
            __builtin_amdgcn_global_load_lds(
                (const __attribute__((address_space(1))) void*)ga,
                (__attribute__((address_space(3))) void*)(&As[buf][idx * 8]),
                16, 0, 0);
        }
    };
    // stage full B K-tile (NF*64 rows x 64 k): NF x gload_lds(16B)/thread
    auto stageB = [&](int buf, int t) {
        #pragma unroll
        for (int q = 0; q < NF; ++q) {
            int idx = q * 512 + tid;
            int row = idx >> 3;                 // 0..NF*64-1
            int slot = (idx & 7) ^ (row & 7);
            int gk = (t << 6) + slot * 8;
            const unsigned short* gb = Wt + (long)(c0 + row) * Kd + gk;
            __builtin_amdgcn_global_load_lds(
                (const __attribute__((address_space(1))) void*)gb,
                (__attribute__((address_space(3))) void*)(&Bs[buf][idx * 8]),
                16, 0, 0);
        }
    };

    f32x4 acc[8][NF] = {};

    // prologue: tiles 0 and 1
    stageA(0, 0); stageB(0, 0);
    stageA(1, 1); stageB(1, 1);
    if (NF == 4) asm volatile("s_waitcnt vmcnt(8)" ::: "memory");  // tile0 landed
    else         asm volatile("s_waitcnt vmcnt(7)" ::: "memory");
    asm volatile("s_barrier" ::: "memory");

    for (int t = 0; t < nt; ++t) {
        const int cur = t & 1;
        const bool do_stage = (t >= 1) && (t + 1 < nt);
        short8 af[4], bv0[NF], bv1[NF];

        // ---- P1 (mh=0, kk=0): A m0..3 + B kk=0; stage A(t+1)
        #pragma unroll
        for (int mm = 0; mm < 4; ++mm) {
            int row = wr * 128 + mm * 16 + lr;
            af[mm] = *(const short8*)(&As[cur][row * 64 + ((lk * 8) ^ swz)]);
        }
        #pragma unroll
        for (int n = 0; n < NF; ++n) {
            int row = wc * (NF * 16) + n * 16 + lr;
            bv0[n] = *(const short8*)(&Bs[cur][row * 64 + ((lk * 8) ^ swz)]);
        }
        if (do_stage) stageA(cur ^ 1, t + 1);
        asm volatile("s_barrier" ::: "memory");
        asm volatile("s_waitcnt lgkmcnt(0)" ::: "memory");
        __builtin_amdgcn_s_setprio(1);
        #pragma unroll
        for (int mm = 0; mm < 4; ++mm)
            #pragma unroll
            for (int n = 0; n < NF; ++n)
                acc[mm][n] = __builtin_amdgcn_mfma_f32_16x16x32_bf16(
                    af[mm], bv0[n], acc[mm][n], 0, 0, 0);
        __builtin_amdgcn_s_setprio(0);
        asm volatile("s_barrier" ::: "memory");

        // ---- P2 (mh=1, kk=0): A m4..7 (reuse bv0); stage B(t+1)
        #pragma unroll
        for (int mm = 0; mm < 4; ++mm) {
            int row = wr * 128 + 64 + mm * 16 + lr;
            af[mm] = *(const short8*)(&As[cur][row * 64 + ((lk * 8) ^ swz)]);
        }
        if (do_stage) stageB(cur ^ 1, t + 1);
        asm volatile("s_barrier" ::: "memory");
        asm volatile("s_waitcnt lgkmcnt(0)" ::: "memory");
        __builtin_amdgcn_s_setprio(1);
        #pragma unroll
        for (int mm = 0; mm < 4; ++mm)
            #pragma unroll
            for (int n = 0; n < NF; ++n)
                acc[4 + mm][n] = __builtin_amdgcn_mfma_f32_16x16x32_bf16(
                    af[mm], bv0[n], acc[4 + mm][n], 0, 0, 0);
        __builtin_amdgcn_s_setprio(0);
        asm volatile("s_barrier" ::: "memory");

        // ---- P3 (mh=0, kk=1): A m0..3 + B kk=1
        #pragma unroll
        for (int mm = 0; mm < 4; ++mm) {
            int row = wr * 128 + mm * 16 + lr;
            af[mm] = *(const short8*)(&As[cur][row * 64 + ((32 + lk * 8) ^ swz)]);
        }
        #pragma unroll
        for (int n = 0; n < NF; ++n) {
            int row = wc * (NF * 16) + n * 16 + lr;
            bv1[n] = *(const short8*)(&Bs[cur][row * 64 + ((32 + lk * 8) ^ swz)]);
        }
        asm volatile("s_barrier" ::: "memory");
        asm volatile("s_waitcnt lgkmcnt(0)" ::: "memory");
        __builtin_amdgcn_s_setprio(1);
        #pragma unroll
        for (int mm = 0; mm < 4; ++mm)
            #pragma unroll
            for (int n = 0; n < NF; ++n)
                acc[mm][n] = __builtin_amdgcn_mfma_f32_16x16x32_bf16(
                    af[mm], bv1[n], acc[mm][n], 0, 0, 0);
        __builtin_amdgcn_s_setprio(0);
        asm volatile("s_barrier" ::: "memory");

        // ---- P4 (mh=1, kk=1): A m4..7 (reuse bv1); tile-boundary wait
        #pragma unroll
        for (int mm = 0; mm < 4; ++mm) {
            int row = wr * 128 + 64 + mm * 16 + lr;
            af[mm] = *(const short8*)(&As[cur][row * 64 + ((32 + lk * 8) ^ swz)]);
        }
        asm volatile("s_barrier" ::: "memory");
        asm volatile("s_waitcnt lgkmcnt(0)" ::: "memory");
        __builtin_amdgcn_s_setprio(1);
        #pragma unroll
        for (int mm = 0; mm < 4; ++mm)
            #pragma unroll
            for (int n = 0; n < NF; ++n)
                acc[4 + mm][n] = __builtin_amdgcn_mfma_f32_16x16x32_bf16(
                    af[mm], bv1[n], acc[4 + mm][n], 0, 0, 0);
        __builtin_amdgcn_s_setprio(0);
        // wait tile t+1's loads (only loads in flight); then release buffers
        if (t + 1 < nt) asm volatile("s_waitcnt vmcnt(0)" ::: "memory");
        asm volatile("s_barrier" ::: "memory");
    }

    // epilogue: C/D layout col=lane&15, row=(lane>>4)*4+reg  [m89/m91 verified]
    const int cb = c0 + wc * (NF * 16);
    #pragma unroll
    for (int n = 0; n < NF; ++n) {
        const int c = cb + n * 16 + lr;
        const float bc = bias[c];
        #pragma unroll
        for (int m = 0; m < 8; ++m) {
            const long r = r0 + wr * 128 + m * 16 + lk * 4;
            #pragma unroll
            for (int j = 0; j < 4; ++j) {
                float v = acc[m][n][j] + bc;
                if (ACT) v = gelu_f(v);
                if (RESID) v += bf2f(resid[(r + j) * N + c]);
                if (OUT_BF16) ((unsigned short*)Cout)[(r + j) * N + c] = f2bf(v);
                else          ((float*)Cout)[(r + j) * N + c] = v;
            }
        }
    }
}

// ---------------------------------------------------------------------------
// Stage A of LN+pool: each block handles 8 of a mention's 32 rows (1 row/wave),
// LN (ac_ln) + score-weight, writes partial sums. grid = (CH/32)*4.
__global__ __launch_bounds__(512) void ln_pool_part_k(
    const unsigned short* __restrict__ cvb, const float* __restrict__ scores,
    const float* __restrict__ ln_s, const float* __restrict__ ln_b,
    float* __restrict__ partial,   // [CH/32][4][768]
    int mbase)
{
    __shared__ float part[8][768];
    int lm = blockIdx.x >> 2, ks = blockIdx.x & 3;
    int gm = mbase + lm;
    int tid = threadIdx.x, lane = tid & 63, wid = tid >> 6;
    int k = ks * 8 + wid;
    const unsigned short* row = cvb + ((long)lm * 32 + k) * Dq;

    float v[12], gs[12], gb[12];
    float s = 0.f, ss = 0.f;
    #pragma unroll
    for (int j = 0; j < 3; ++j) {
        int col = j * 256 + lane * 4;
        ushort4v u = *(const ushort4v*)(row + col);
        float4 g = *reinterpret_cast<const float4*>(ln_s + col);
        float4 h = *reinterpret_cast<const float4*>(ln_b + col);
        #pragma unroll
        for (int t = 0; t < 4; ++t) {
            float x = bf2f(u[t]);
            v[j * 4 + t] = x;
            s += x; ss += x * x;
        }
        gs[j * 4 + 0] = g.x; gs[j * 4 + 1] = g.y; gs[j * 4 + 2] = g.z; gs[j * 4 + 3] = g.w;
        gb[j * 4 + 0] = h.x; gb[j * 4 + 1] = h.y; gb[j * 4 + 2] = h.z; gb[j * 4 + 3] = h.w;
    }
    #pragma unroll
    for (int off = 32; off > 0; off >>= 1) {
        s  += __shfl_xor(s, off, 64);
        ss += __shfl_xor(ss, off, 64);
    }
    float mu = s * (1.0f / Dq);
    float var = ss * (1.0f / Dq) - mu * mu;
    float rstd = rsqrtf(var + 1e-12f);
    float sc = scores[gm * 32 + k];
    #pragma unroll
    for (int j = 0; j < 3; ++j) {
        int col = j * 256 + lane * 4;
        #pragma unroll
        for (int t = 0; t < 4; ++t)
            part[wid][col + t] = sc * ((v[j * 4 + t] - mu) * rstd * gs[j * 4 + t] + gb[j * 4 + t]);
    }
    __syncthreads();
    for (int d = tid; d < Dq; d += 512) {
        float acc = 0.f;
        #pragma unroll
        for (int w = 0; w < 8; ++w) acc += part[w][d];
        partial[((long)lm * 4 + ks) * Dq + d] = acc;
    }
}

// Stage B: pooled[m] = sum of 4 partials. grid = CH/32.
__global__ __launch_bounds__(256) void ln_pool_comb_k(
    const float* __restrict__ partial, float* __restrict__ pooledf,
    unsigned short* __restrict__ pooledb, int mbase)
{
    int lm = blockIdx.x, gm = mbase + lm;
    int tid = threadIdx.x;
    for (int d = tid; d < Dq; d += 256) {
        const float* p = partial + (long)lm * 4 * Dq + d;
        float s = p[0] + p[Dq] + p[2 * Dq] + p[3 * Dq];
        pooledf[(long)gm * Dq + d] = s;
        pooledb[(long)gm * Dq + d] = f2bf(s);
    }
}

// ---------------------------------------------------------------------------
// Per-mention: y = LN(pu + pooled; pl_ln) * mask; atomicAdd into out[(b,s)] row.
__global__ __launch_bounds__(256) void ln_mask_scatter_k(
    const float* __restrict__ pu, const float* __restrict__ pooled,
    const float* __restrict__ ln_s, const float* __restrict__ ln_b,
    const float* __restrict__ mask,
    const int* __restrict__ bpos, const int* __restrict__ spos,
    float* __restrict__ out)
{
    __shared__ float sm[8];
    int m = blockIdx.x;
    int tid = threadIdx.x;
    float v[3];
    float s = 0.f, ss = 0.f;
    #pragma unroll
    for (int j = 0; j < 3; ++j) {
        int d = tid + j * 256;
        v[j] = pu[(long)m * Dq + d] + pooled[(long)m * Dq + d];
        s += v[j]; ss += v[j] * v[j];
    }
    block_reduce2(s, ss, sm);
    float mu = s * (1.0f / Dq);
    float var = ss * (1.0f / Dq) - mu * mu;
    float rstd = rsqrtf(var + 1e-12f);
    float mk = mask[m];
    long orow = ((long)bpos[m] * Tq + spos[m]) * Dq;
    #pragma unroll
    for (int j = 0; j < 3; ++j) {
        int d = tid + j * 256;
        float y = ((v[j] - mu) * rstd * ln_s[d] + ln_b[d]) * mk;
        atomicAdd(&out[orow + d], y);
    }
}

// ---------------------------------------------------------------------------
// Final in-place LN over each [768] row of out.
__global__ __launch_bounds__(256) void final_ln_k(
    float* __restrict__ out, const float* __restrict__ ln_s,
    const float* __restrict__ ln_b)
{
    __shared__ float sm[8];
    int tid = threadIdx.x;
    float* row = out + (long)blockIdx.x * Dq;
    float v[3];
    float s = 0.f, ss = 0.f;
    #pragma unroll
    for (int j = 0; j < 3; ++j) {
        v[j] = row[tid + j * 256];
        s += v[j]; ss += v[j] * v[j];
    }
    block_reduce2(s, ss, sm);
    float mu = s * (1.0f / Dq);
    float var = ss * (1.0f / Dq) - mu * mu;
    float rstd = rsqrtf(var + 1e-12f);
    #pragma unroll
    for (int j = 0; j < 3; ++j) {
        int d = tid + j * 256;
        row[d] = (v[j] - mu) * rstd * ln_s[d] + ln_b[d];
    }
}

// ---------------------------------------------------------------------------
extern "C" void kernel_launch(void* const* d_in, const int* in_sizes, int n_in,
                              void* d_out, int out_size, void* d_ws, size_t ws_size,
                              hipStream_t stream) {
    const float* enc    = (const float*)d_in[0];
    const float* rv     = (const float*)d_in[1];
    const float* scores = (const float*)d_in[2];
    const int*   bpos   = (const int*)d_in[3];
    const int*   spos   = (const int*)d_in[4];
    const int*   epos   = (const int*)d_in[5];
    const float* mask   = (const float*)d_in[6];
    const float* vp_w   = (const float*)d_in[7];
    const float* vp_b   = (const float*)d_in[8];
    const float* cm_w   = (const float*)d_in[9];
    const float* cm_b   = (const float*)d_in[10];
    const float* cd_w   = (const float*)d_in[11];
    const float* cd_b   = (const float*)d_in[12];
    const float* ac_w1  = (const float*)d_in[13];
    const float* ac_b1  = (const float*)d_in[14];
    const float* ac_w2  = (const float*)d_in[15];
    const float* ac_b2  = (const float*)d_in[16];
    const float* ac_ln_s = (const float*)d_in[17];
    const float* ac_ln_b = (const float*)d_in[18];
    const float* pl_w1  = (const float*)d_in[19];
    const float* pl_b1  = (const float*)d_in[20];
    const float* pl_w2  = (const float*)d_in[21];
    const float* pl_b2  = (const float*)d_in[22];
    const float* pl_ln_s = (const float*)d_in[23];
    const float* pl_ln_b = (const float*)d_in[24];
    const float* ln_s   = (const float*)d_in[25];
    const float* ln_b   = (const float*)d_in[26];
    float* out = (float*)d_out;

    // workspace layout (bytes), ~224 MB of the confirmed 256 MiB
    char* wsb = (char*)d_ws;
    unsigned short* wt_cm = (unsigned short*)wsb; wsb += (size_t)1024 * 256 * 2;
    unsigned short* wt_cd = (unsigned short*)wsb; wsb += (size_t)768 * 1024 * 2;
    unsigned short* wt_a1 = (unsigned short*)wsb; wsb += (size_t)1024 * 768 * 2;
    unsigned short* wt_a2 = (unsigned short*)wsb; wsb += (size_t)768 * 1024 * 2;
    unsigned short* wt_p1 = (unsigned short*)wsb; wsb += (size_t)1024 * 768 * 2;
    unsigned short* wt_p2 = (unsigned short*)wsb; wsb += (size_t)768 * 1024 * 2;
    unsigned short* wt_vp = (unsigned short*)wsb; wsb += (size_t)128 * 1536 * 2;
    unsigned short* pmvb  = (unsigned short*)wsb; wsb += (size_t)Mq * Rq * 2;
    unsigned short* rvb   = (unsigned short*)wsb; wsb += (size_t)NROWS * Rq * 2;
    unsigned short* catenc = (unsigned short*)wsb; wsb += (size_t)Mq * 1536 * 2;
    unsigned short* hb    = (unsigned short*)wsb; wsb += (size_t)CH * Hq * 2;
    unsigned short* tb    = (unsigned short*)wsb; wsb += (size_t)CH * Dq * 2;
    unsigned short* cvb   = (unsigned short*)wsb; wsb += (size_t)CH * Dq * 2;
    float* partial = (float*)wsb; wsb += (size_t)(CH / Kq) * 4 * Dq * 4;
    float* pooledf = (float*)wsb; wsb += (size_t)Mq * Dq * 4;
    unsigned short* pooledb = (unsigned short*)wsb; wsb += (size_t)Mq * Dq * 2;
    float* puf     = (float*)wsb; wsb += (size_t)Mq * Dq * 4;

    // out = encoded_input (base for scatter-add)
    hipMemcpyAsync(out, enc, (size_t)Bq * Tq * Dq * sizeof(float),
                   hipMemcpyDeviceToDevice, stream);

    // weights -> bf16 transposed [N][K]; rv -> bf16
    wtrans_k<<<dim3(1024 / 32, 256 / 32), 256, 0, stream>>>(cm_w, wt_cm, 256, 1024);
    wtrans_k<<<dim3(768 / 32, 1024 / 32), 256, 0, stream>>>(cd_w, wt_cd, 1024, 768);
    wtrans_k<<<dim3(1024 / 32, 768 / 32), 256, 0, stream>>>(ac_w1, wt_a1, 768, 1024);
    wtrans_k<<<dim3(768 / 32, 1024 / 32), 256, 0, stream>>>(ac_w2, wt_a2, 1024, 768);
    wtrans_k<<<dim3(1024 / 32, 768 / 32), 256, 0, stream>>>(pl_w1, wt_p1, 768, 1024);
    wtrans_k<<<dim3(768 / 32, 1024 / 32), 256, 0, stream>>>(pl_w2, wt_p2, 1024, 768);
    wtrans_k<<<dim3(128 / 32, 1536 / 32), 256, 0, stream>>>(vp_w, wt_vp, 1536, 128);
    rv2bf_k<<<(NROWS * Rq) / (256 * 8), 256, 0, stream>>>(rv, rvb);

    // pmv = concat(start,end) @ vp_w + vp_b  as bf16 MFMA GEMM (128^2 kernel)
    gather_enc_k<<<Mq, 192, 0, stream>>>(enc, bpos, spos, epos, catenc);
    mgemm_k<0, 1, 0, 0><<<dim3(Mq / 128, 1), 256, 0, stream>>>(
        catenc, wt_vp, vp_b, pmvb, nullptr, 1536, Rq, nullptr, nullptr, 0);

    for (int c = 0; c < NCH; ++c) {
        int row_base = c * CH;
        int mbase = c * (CH / Kq);
        // h1 = gelu(concat(pmv,rv) @ cm_w + cm_b)   [CH,1024] bf16  (BN=256)
        mg8_k<1, 1, 0, 1, 4><<<dim3(CH / 256, Hq / 256), 512, 0, stream>>>(
            nullptr, wt_cm, cm_b, hb, nullptr, 2 * Rq, Hq, pmvb, rvb, row_base);
        // t = h1 @ cd_w + cd_b                      [CH,768] bf16  (BN=192)
        mg8_k<0, 1, 0, 0, 3><<<dim3(CH / 256, Dq / 192), 512, 0, stream>>>(
            hb, wt_cd, cd_b, tb, nullptr, Hq, Dq, nullptr, nullptr, 0);
        // h2 = gelu(t @ ac_w1 + ac_b1)              [CH,1024] bf16  (BN=256)
        mg8_k<1, 1, 0, 0, 4><<<dim3(CH / 256, Hq / 256), 512, 0, stream>>>(
            tb, wt_a1, ac_b1, hb, nullptr, Dq, Hq, nullptr, nullptr, 0);
        // cv = h2 @ ac_w2 + ac_b2 + t               [CH,768] bf16  (BN=192)
        mg8_k<0, 1, 1, 0, 3><<<dim3(CH / 256, Dq / 192), 512, 0, stream>>>(
            hb, wt_a2, ac_b2, cvb, tb, Hq, Dq, nullptr, nullptr, 0);
        // LN + score-weighted pool (split-k over 4 blocks/mention, then combine)
        ln_pool_part_k<<<(CH / Kq) * 4, 512, 0, stream>>>(
            cvb, scores, ac_ln_s, ac_ln_b, partial, mbase);
        ln_pool_comb_k<<<CH / Kq, 256, 0, stream>>>(partial, pooledf, pooledb, mbase);
    }

    // pooled MLP (M=2048 -> 128^2 kernel)
    mgemm_k<1, 1, 0, 0><<<dim3(Mq / 128, Hq / 128), 256, 0, stream>>>(
        pooledb, wt_p1, pl_b1, hb, nullptr, Dq, Hq, nullptr, nullptr, 0);
    mgemm_k<0, 0, 0, 0><<<dim3(Mq / 128, Dq / 128), 256, 0, stream>>>(
        hb, wt_p2, pl_b2, puf, nullptr, Hq, Dq, nullptr, nullptr, 0);

    // LN(pu + pooled) * mask, scatter-add into out
    ln_mask_scatter_k<<<Mq, 256, 0, stream>>>(puf, pooledf, pl_ln_s, pl_ln_b,
                                              mask, bpos, spos, out);

    // final LN over every row of out
    final_ln_k<<<Bq * Tq, 256, 0, stream>>>(out, ln_s, ln_b);
}

// Round 15
// 675.285 us; speedup vs baseline: 1.2439x; 1.0580x over previous
//
#include <hip/hip_runtime.h>
#include <hip/hip_bf16.h>

// Problem constants
#define Bq 32
#define Tq 512
#define Dq 768
#define Mq 2048
#define Kq 32
#define Rq 128
#define Hq 1024
#define NROWS (Mq * Kq)   // 65536
#define CH 32768          // rows per chunk (1024 mentions)
#define NCH (NROWS / CH)  // 2

typedef short short8 __attribute__((ext_vector_type(8)));
typedef unsigned short ushort4v __attribute__((ext_vector_type(4)));
typedef float f32x4 __attribute__((ext_vector_type(4)));
typedef float f32x16 __attribute__((ext_vector_type(16)));

__device__ __forceinline__ unsigned short f2bf(float f) {
    union { float f; unsigned u; } v; v.f = f;
    unsigned r = v.u + 0x7FFFu + ((v.u >> 16) & 1u);   // RNE
    return (unsigned short)(r >> 16);
}
__device__ __forceinline__ float bf2f(unsigned short h) {
    union { unsigned u; float f; } v; v.u = ((unsigned)h) << 16;
    return v.f;
}
// gelu(tanh approx) = x * sigmoid(2*0.79788456*(x + 0.044715 x^3))
__device__ __forceinline__ float gelu_f(float x) {
    float u = x * (1.5957691216057308f + 0.07135481622212034f * x * x);
    return x / (1.0f + __expf(-u));
}

// Block-wide reduce of two values (sum). 256 threads = 4 waves.
__device__ __forceinline__ void block_reduce2(float& a, float& b, float* sm) {
    #pragma unroll
    for (int off = 32; off > 0; off >>= 1) {
        a += __shfl_down(a, off, 64);
        b += __shfl_down(b, off, 64);
    }
    int lane = threadIdx.x & 63, wid = threadIdx.x >> 6;
    if (lane == 0) { sm[wid * 2] = a; sm[wid * 2 + 1] = b; }
    __syncthreads();
    if (threadIdx.x == 0) {
        float sa = 0.f, sb = 0.f;
        #pragma unroll
        for (int w = 0; w < 4; ++w) { sa += sm[w * 2]; sb += sm[w * 2 + 1]; }
        sm[0] = sa; sm[1] = sb;
    }
    __syncthreads();
    a = sm[0]; b = sm[1];
    __syncthreads();
}

// ---------------------------------------------------------------------------
// Weight transpose + f32->bf16: Wt[n][k] = bf16(W[k][n])
__global__ __launch_bounds__(256) void wtrans_k(
    const float* __restrict__ W, unsigned short* __restrict__ Wt, int K, int N)
{
    __shared__ unsigned short t[32][33];
    int n0 = blockIdx.x * 32, k0 = blockIdx.y * 32;
    int tx = threadIdx.x & 31, ty = threadIdx.x >> 5;
    #pragma unroll
    for (int i = 0; i < 32; i += 8)
        t[ty + i][tx] = f2bf(W[(long)(k0 + ty + i) * N + n0 + tx]);
    __syncthreads();
    #pragma unroll
    for (int i = 0; i < 32; i += 8)
        Wt[(long)(n0 + ty + i) * K + k0 + tx] = t[tx][ty + i];
}

// ---------------------------------------------------------------------------
// rv (f32) -> rvb (bf16), whole tensor [NROWS][128]
__global__ __launch_bounds__(256) void rv2bf_k(
    const float* __restrict__ rv, unsigned short* __restrict__ rvb)
{
    long i = ((long)blockIdx.x * 256 + threadIdx.x) * 8;
    float4 a = *reinterpret_cast<const float4*>(rv + i);
    float4 b = *reinterpret_cast<const float4*>(rv + i + 4);
    unsigned short v[8] = {f2bf(a.x), f2bf(a.y), f2bf(a.z), f2bf(a.w),
                           f2bf(b.x), f2bf(b.y), f2bf(b.z), f2bf(b.w)};
    *(short8*)(rvb + i) = *(short8*)v;
}

// ---------------------------------------------------------------------------
// Gather concat(start,end) encodings as bf16: cat[m][1536]
__global__ __launch_bounds__(192) void gather_enc_k(
    const float* __restrict__ enc, const int* __restrict__ bpos,
    const int* __restrict__ spos, const int* __restrict__ epos,
    unsigned short* __restrict__ cat)
{
    int m = blockIdx.x;
    int t = threadIdx.x;                 // 0..191
    int b = bpos[m];
    int pos = (t < 96) ? spos[m] : epos[m];
    int off = (t < 96) ? t * 8 : (t - 96) * 8;
    const float4* s = reinterpret_cast<const float4*>(enc + ((long)b * Tq + pos) * Dq + off);
    float4 a = s[0], c = s[1];
    unsigned short v[8] = {f2bf(a.x), f2bf(a.y), f2bf(a.z), f2bf(a.w),
                           f2bf(c.x), f2bf(c.y), f2bf(c.z), f2bf(c.w)};
    *(short8*)(cat + (long)m * 1536 + t * 8) = *(short8*)v;
}

// ---------------------------------------------------------------------------
// 128x128-tile bf16 MFMA GEMM (verified depth-2 counted-vmcnt pipeline).
// Used for the small-M GEMMs (pmv projection, pooled MLP).
template <int ACT, int OUT_BF16, int RESID, int CONCAT>
__global__ __launch_bounds__(256) void mgemm_k(
    const unsigned short* __restrict__ A,
    const unsigned short* __restrict__ Wt,
    const float* __restrict__ bias,
    void* __restrict__ Cout,
    const unsigned short* __restrict__ resid,
    int Kd, int N,
    const unsigned short* __restrict__ pmvb,
    const unsigned short* __restrict__ rvb,
    int row_base)
{
    __shared__ __align__(16) unsigned short AsLin[2][128 * 32];
    __shared__ __align__(16) unsigned short BsLin[2][128 * 32];
    const int tid = threadIdx.x;
    const int w = tid >> 6, lane = tid & 63;
    const int wr = w >> 1, wc = w & 1;
    const int lr = lane & 15, lk = lane >> 4;
    const long r0 = (long)blockIdx.x * 128;
    const int c0 = blockIdx.y * 128;
    const int nt = Kd >> 5;

    auto stage = [&](int buf, int t) {
        const int k0 = t << 5;
        #pragma unroll
        for (int cc = 0; cc < 2; ++cc) {
            int idx = (w * 2 + cc) * 64 + lane;
            int row = idx >> 2, kc = idx & 3;
            int kcol = k0 + kc * 8;
            const unsigned short* ga;
            if (CONCAT) {
                long gr = row_base + r0 + row;
                ga = (kcol < 128) ? pmvb + ((gr >> 5) << 7) + kcol
                                  : rvb + (gr << 7) + (kcol - 128);
            } else {
                ga = A + (r0 + row) * Kd + kcol;
            }
            __builtin_amdgcn_global_load_lds(
                (const __attribute__((address_space(1))) void*)ga,
                (__attribute__((address_space(3))) void*)(&AsLin[buf][(w * 2 + cc) * 512]),
                16, 0, 0);
            const unsigned short* gb = Wt + (long)(c0 + row) * Kd + kcol;
            __builtin_amdgcn_global_load_lds(
                (const __attribute__((address_space(1))) void*)gb,
                (__attribute__((address_space(3))) void*)(&BsLin[buf][(w * 2 + cc) * 512]),
                16, 0, 0);
        }
    };

    f32x4 acc[4][4] = {};

    stage(0, 0);
    if (nt > 1) stage(1, 1);

    for (int t = 0; t < nt; ++t) {
        const int cur = t & 1;
        if (t + 1 < nt) asm volatile("s_waitcnt vmcnt(4)" ::: "memory");
        else            asm volatile("s_waitcnt vmcnt(0)" ::: "memory");
        asm volatile("s_barrier" ::: "memory");

        short8 af[4], bv[4];
        #pragma unroll
        for (int m = 0; m < 4; ++m)
            af[m] = *(const short8*)(&AsLin[cur][(wr * 64 + m * 16 + lr) * 32 + lk * 8]);
        #pragma unroll
        for (int n = 0; n < 4; ++n)
            bv[n] = *(const short8*)(&BsLin[cur][(wc * 64 + n * 16 + lr) * 32 + lk * 8]);

        asm volatile("s_waitcnt lgkmcnt(0)" ::: "memory");
        asm volatile("s_barrier" ::: "memory");

        if (t + 2 < nt) stage(cur, t + 2);

        #pragma unroll
        for (int m = 0; m < 4; ++m)
            #pragma unroll
            for (int n = 0; n < 4; ++n)
                acc[m][n] = __builtin_amdgcn_mfma_f32_16x16x32_bf16(
                    af[m], bv[n], acc[m][n], 0, 0, 0);
    }

    const int cb = c0 + wc * 64;
    #pragma unroll
    for (int n = 0; n < 4; ++n) {
        const int c = cb + n * 16 + lr;
        const float bc = bias[c];
        #pragma unroll
        for (int m = 0; m < 4; ++m) {
            const long r = r0 + wr * 64 + m * 16 + lk * 4;
            #pragma unroll
            for (int j = 0; j < 4; ++j) {
                float v = acc[m][n][j] + bc;
                if (ACT) v = gelu_f(v);
                if (RESID) v += bf2f(resid[(r + j) * N + c]);
                if (OUT_BF16) ((unsigned short*)Cout)[(r + j) * N + c] = f2bf(v);
                else          ((float*)Cout)[(r + j) * N + c] = v;
            }
        }
    }
}

// ---------------------------------------------------------------------------
// 256xBN bf16 MFMA GEMM, 32x32x16 MFMA inside the VERIFIED round-13 4-phase
// schedule (identical staging, barriers, vmcnt counts; drain at tile boundary).
// 8 waves; NF=4: 2M x 4N waves, wave tile 128x64 (4 Mblk x 2 Nblk of 32x32);
// NF=3: 4M x 2N waves, wave tile 64x96 (2 Mblk x 3 Nblk).
// T2 XOR-swizzle (both-sides involution, row&7 == lane&7) + T5 setprio +
// T1 XCD remap. A-frag: lane l -> row=l&31, k=(l>>5)*8 (contiguous 8);
// C/D: col=lane&31, row=(reg&3)+8*(reg>>2)+4*(lane>>5)  [m74/m101 verified].
template <int ACT, int OUT_BF16, int RESID, int CONCAT, int NF>
__global__ __launch_bounds__(512, 1) void mg8_k(
    const unsigned short* __restrict__ A,
    const unsigned short* __restrict__ Wt,
    const float* __restrict__ bias,
    void* __restrict__ Cout,
    const unsigned short* __restrict__ resid,
    int Kd, int N,
    const unsigned short* __restrict__ pmvb,
    const unsigned short* __restrict__ rvb,
    int row_base)
{
    constexpr int MB = (NF == 4) ? 2 : 1;   // Mblks per mh-half
    constexpr int NB = (NF == 4) ? 2 : 3;   // Nblks per wave
    __shared__ __align__(16) unsigned short As[2][256 * 64];
    __shared__ __align__(16) unsigned short Bs[2][NF * 64 * 64];
    const int tid = threadIdx.x;
    const int w = tid >> 6, lane = tid & 63;
    const int wr = (NF == 4) ? (w >> 2) : (w >> 1);
    const int wc = (NF == 4) ? (w & 3) : (w & 1);
    const int wrow = (NF == 4) ? wr * 128 : wr * 64;
    const int wcol = (NF == 4) ? wc * 64 : wc * 96;
    const int l31 = lane & 31, lhi = lane >> 5;

    // XCD-clustered bijective remap (row-panel sharers on one XCD)
    const int rows = gridDim.x, cols = gridDim.y;
    const int lin = blockIdx.x + blockIdx.y * rows;
    const int xcd = lin & 7, sq = lin >> 3;
    const int rpx = rows >> 3;
    const int bcol = sq % cols;
    const int brow = xcd * rpx + sq / cols;

    const long r0 = (long)brow * 256;
    const int c0 = bcol * (NF * 64);
    const int nt = Kd >> 6;
    const int swz = (lane & 7) << 3;    // frag-read XOR, in shorts (16B slots)

    // stage one A unit q (rows [q*64,(q+1)*64), all 64 k): 1 gload/thread
    auto stageAu = [&](int buf, int t, int q) {
        int idx = q * 512 + tid;
        int row = idx >> 3;
        int slot = (idx & 7) ^ (row & 7);
        int gk = (t << 6) + slot * 8;
        const unsigned short* ga;
        if (CONCAT) {
            long gr = row_base + r0 + row;
            ga = (gk < 128) ? pmvb + ((gr >> 5) << 7) + gk
                            : rvb + (gr << 7) + (gk - 128);
        } else {
            ga = A + (r0 + row) * Kd + gk;
        }
        __builtin_amdgcn_global_load_lds(
            (const __attribute__((address_space(1))) void*)ga,
            (__attribute__((address_space(3))) void*)(&As[buf][idx * 8]),
            16, 0, 0);
    };
    auto stageBu = [&](int buf, int t, int q) {
        int idx = q * 512 + tid;
        int row = idx >> 3;
        int slot = (idx & 7) ^ (row & 7);
        int gk = (t << 6) + slot * 8;
        const unsigned short* gb = Wt + (long)(c0 + row) * Kd + gk;
        __builtin_amdgcn_global_load_lds(
            (const __attribute__((address_space(1))) void*)gb,
            (__attribute__((address_space(3))) void*)(&Bs[buf][idx * 8]),
            16, 0, 0);
    };
    auto stageA = [&](int buf, int t) {
        #pragma unroll
        for (int q = 0; q < 4; ++q) stageAu(buf, t, q);
    };
    auto stageB = [&](int buf, int t) {
        #pragma unroll
        for (int q = 0; q < NF; ++q) stageBu(buf, t, q);
    };

    // frag readers: A row = wrow + (mh*MB+m)*32 + l31; col = kk*32+s*16+lhi*8
    auto rdA = [&](int cur, int mh, int m, int kk, int s) -> short8 {
        int row = wrow + (mh * MB + m) * 32 + l31;
        int col = kk * 32 + s * 16 + lhi * 8;
        return *(const short8*)(&As[cur][row * 64 + (col ^ swz)]);
    };
    auto rdB = [&](int cur, int n, int kk, int s) -> short8 {
        int row = wcol + n * 32 + l31;
        int col = kk * 32 + s * 16 + lhi * 8;
        return *(const short8*)(&Bs[cur][row * 64 + (col ^ swz)]);
    };

    f32x16 acc[2 * MB][NB] = {};

    // ---- prologue: tiles 0 and 1 (identical to round-13)
    stageA(0, 0); stageB(0, 0);
    stageA(1, 1); stageB(1, 1);
    if (NF == 4) asm volatile("s_waitcnt vmcnt(8)" ::: "memory");
    else         asm volatile("s_waitcnt vmcnt(7)" ::: "memory");
    asm volatile("s_barrier" ::: "memory");

    for (int t = 0; t < nt; ++t) {
        const int cur = t & 1;
        const bool do_stage = (t >= 1) && (t + 1 < nt);
        short8 af[MB][2], bv0[NB][2], bv1[NB][2];

        // ---- P1: mh0,kk0 + B kk0; stage A(t+1)
        #pragma unroll
        for (int m = 0; m < MB; ++m)
            #pragma unroll
            for (int s = 0; s < 2; ++s) af[m][s] = rdA(cur, 0, m, 0, s);
        #pragma unroll
        for (int n = 0; n < NB; ++n)
            #pragma unroll
            for (int s = 0; s < 2; ++s) bv0[n][s] = rdB(cur, n, 0, s);
        if (do_stage) stageA(cur ^ 1, t + 1);
        asm volatile("s_barrier" ::: "memory");
        asm volatile("s_waitcnt lgkmcnt(0)" ::: "memory");
        __builtin_amdgcn_s_setprio(1);
        #pragma unroll
        for (int m = 0; m < MB; ++m)
            #pragma unroll
            for (int n = 0; n < NB; ++n)
                #pragma unroll
                for (int s = 0; s < 2; ++s)
                    acc[m][n] = __builtin_amdgcn_mfma_f32_32x32x16_bf16(
                        af[m][s], bv0[n][s], acc[m][n], 0, 0, 0);
        __builtin_amdgcn_s_setprio(0);
        asm volatile("s_barrier" ::: "memory");

        // ---- P2: mh1,kk0 (reuse bv0); stage B(t+1)
        #pragma unroll
        for (int m = 0; m < MB; ++m)
            #pragma unroll
            for (int s = 0; s < 2; ++s) af[m][s] = rdA(cur, 1, m, 0, s);
        if (do_stage) stageB(cur ^ 1, t + 1);
        asm volatile("s_barrier" ::: "memory");
        asm volatile("s_waitcnt lgkmcnt(0)" ::: "memory");
        __builtin_amdgcn_s_setprio(1);
        #pragma unroll
        for (int m = 0; m < MB; ++m)
            #pragma unroll
            for (int n = 0; n < NB; ++n)
                #pragma unroll
                for (int s = 0; s < 2; ++s)
                    acc[MB + m][n] = __builtin_amdgcn_mfma_f32_32x32x16_bf16(
                        af[m][s], bv0[n][s], acc[MB + m][n], 0, 0, 0);
        __builtin_amdgcn_s_setprio(0);
        asm volatile("s_barrier" ::: "memory");

        // ---- P3: mh0,kk1 + B kk1
        #pragma unroll
        for (int m = 0; m < MB; ++m)
            #pragma unroll
            for (int s = 0; s < 2; ++s) af[m][s] = rdA(cur, 0, m, 1, s);
        #pragma unroll
        for (int n = 0; n < NB; ++n)
            #pragma unroll
            for (int s = 0; s < 2; ++s) bv1[n][s] = rdB(cur, n, 1, s);
        asm volatile("s_barrier" ::: "memory");
        asm volatile("s_waitcnt lgkmcnt(0)" ::: "memory");
        __builtin_amdgcn_s_setprio(1);
        #pragma unroll
        for (int m = 0; m < MB; ++m)
            #pragma unroll
            for (int n = 0; n < NB; ++n)
                #pragma unroll
                for (int s = 0; s < 2; ++s)
                    acc[m][n] = __builtin_amdgcn_mfma_f32_32x32x16_bf16(
                        af[m][s], bv1[n][s], acc[m][n], 0, 0, 0);
        __builtin_amdgcn_s_setprio(0);
        asm volatile("s_barrier" ::: "memory");

        // ---- P4: mh1,kk1 (reuse bv1); tile-boundary drain
        #pragma unroll
        for (int m = 0; m < MB; ++m)
            #pragma unroll
            for (int s = 0; s < 2; ++s) af[m][s] = rdA(cur, 1, m, 1, s);
        asm volatile("s_barrier" ::: "memory");
        asm volatile("s_waitcnt lgkmcnt(0)" ::: "memory");
        __builtin_amdgcn_s_setprio(1);
        #pragma unroll
        for (int m = 0; m < MB; ++m)
            #pragma unroll
            for (int n = 0; n < NB; ++n)
                #pragma unroll
                for (int s = 0; s < 2; ++s)
                    acc[MB + m][n] = __builtin_amdgcn_mfma_f32_32x32x16_bf16(
                        af[m][s], bv1[n][s], acc[MB + m][n], 0, 0, 0);
        __builtin_amdgcn_s_setprio(0);
        if (t + 1 < nt) asm volatile("s_waitcnt vmcnt(0)" ::: "memory");
        asm volatile("s_barrier" ::: "memory");
    }

    // epilogue: 32x32 C/D layout col=lane&31, row=(reg&3)+8*(reg>>2)+4*(lane>>5)
    #pragma unroll
    for (int n = 0; n < NB; ++n) {
        const int c = c0 + wcol + n * 32 + l31;
        const float bc = bias[c];
        #pragma unroll
        for (int mb = 0; mb < 2 * MB; ++mb) {
            const long rbase = r0 + wrow + mb * 32 + 4 * lhi;
            #pragma unroll
            for (int reg = 0; reg < 16; ++reg) {
                const long r = rbase + (reg & 3) + 8 * (reg >> 2);
                float v = acc[mb][n][reg] + bc;
                if (ACT) v = gelu_f(v);
                if (RESID) v += bf2f(resid[r * N + c]);
                if (OUT_BF16) ((unsigned short*)Cout)[r * N + c] = f2bf(v);
                else          ((float*)Cout)[r * N + c] = v;
            }
        }
    }
}

// ---------------------------------------------------------------------------
// Stage A of LN+pool: each block handles 8 of a mention's 32 rows (1 row/wave),
// LN (ac_ln) + score-weight, writes partial sums. grid = (CH/32)*4.
__global__ __launch_bounds__(512) void ln_pool_part_k(
    const unsigned short* __restrict__ cvb, const float* __restrict__ scores,
    const float* __restrict__ ln_s, const float* __restrict__ ln_b,
    float* __restrict__ partial,   // [CH/32][4][768]
    int mbase)
{
    __shared__ float part[8][768];
    int lm = blockIdx.x >> 2, ks = blockIdx.x & 3;
    int gm = mbase + lm;
    int tid = threadIdx.x, lane = tid & 63, wid = tid >> 6;
    int k = ks * 8 + wid;
    const unsigned short* row = cvb + ((long)lm * 32 + k) * Dq;

    float v[12], gs[12], gb[12];
    float s = 0.f, ss = 0.f;
    #pragma unroll
    for (int j = 0; j < 3; ++j) {
        int col = j * 256 + lane * 4;
        ushort4v u = *(const ushort4v*)(row + col);
        float4 g = *reinterpret_cast<const float4*>(ln_s + col);
        float4 h = *reinterpret_cast<const float4*>(ln_b + col);
        #pragma unroll
        for (int t = 0; t < 4; ++t) {
            float x = bf2f(u[t]);
            v[j * 4 + t] = x;
            s += x; ss += x * x;
        }
        gs[j * 4 + 0] = g.x; gs[j * 4 + 1] = g.y; gs[j * 4 + 2] = g.z; gs[j * 4 + 3] = g.w;
        gb[j * 4 + 0] = h.x; gb[j * 4 + 1] = h.y; gb[j * 4 + 2] = h.z; gb[j * 4 + 3] = h.w;
    }
    #pragma unroll
    for (int off = 32; off > 0; off >>= 1) {
        s  += __shfl_xor(s, off, 64);
        ss += __shfl_xor(ss, off, 64);
    }
    float mu = s * (1.0f / Dq);
    float var = ss * (1.0f / Dq) - mu * mu;
    float rstd = rsqrtf(var + 1e-12f);
    float sc = scores[gm * 32 + k];
    #pragma unroll
    for (int j = 0; j < 3; ++j) {
        int col = j * 256 + lane * 4;
        #pragma unroll
        for (int t = 0; t < 4; ++t)
            part[wid][col + t] = sc * ((v[j * 4 + t] - mu) * rstd * gs[j * 4 + t] + gb[j * 4 + t]);
    }
    __syncthreads();
    for (int d = tid; d < Dq; d += 512) {
        float acc = 0.f;
        #pragma unroll
        for (int w = 0; w < 8; ++w) acc += part[w][d];
        partial[((long)lm * 4 + ks) * Dq + d] = acc;
    }
}

// Stage B: pooled[m] = sum of 4 partials. grid = CH/32.
__global__ __launch_bounds__(256) void ln_pool_comb_k(
    const float* __restrict__ partial, float* __restrict__ pooledf,
    unsigned short* __restrict__ pooledb, int mbase)
{
    int lm = blockIdx.x, gm = mbase + lm;
    int tid = threadIdx.x;
    for (int d = tid; d < Dq; d += 256) {
        const float* p = partial + (long)lm * 4 * Dq + d;
        float s = p[0] + p[Dq] + p[2 * Dq] + p[3 * Dq];
        pooledf[(long)gm * Dq + d] = s;
        pooledb[(long)gm * Dq + d] = f2bf(s);
    }
}

// ---------------------------------------------------------------------------
// Per-mention: y = LN(pu + pooled; pl_ln) * mask; atomicAdd into out[(b,s)] row.
__global__ __launch_bounds__(256) void ln_mask_scatter_k(
    const float* __restrict__ pu, const float* __restrict__ pooled,
    const float* __restrict__ ln_s, const float* __restrict__ ln_b,
    const float* __restrict__ mask,
    const int* __restrict__ bpos, const int* __restrict__ spos,
    float* __restrict__ out)
{
    __shared__ float sm[8];
    int m = blockIdx.x;
    int tid = threadIdx.x;
    float v[3];
    float s = 0.f, ss = 0.f;
    #pragma unroll
    for (int j = 0; j < 3; ++j) {
        int d = tid + j * 256;
        v[j] = pu[(long)m * Dq + d] + pooled[(long)m * Dq + d];
        s += v[j]; ss += v[j] * v[j];
    }
    block_reduce2(s, ss, sm);
    float mu = s * (1.0f / Dq);
    float var = ss * (1.0f / Dq) - mu * mu;
    float rstd = rsqrtf(var + 1e-12f);
    float mk = mask[m];
    long orow = ((long)bpos[m] * Tq + spos[m]) * Dq;
    #pragma unroll
    for (int j = 0; j < 3; ++j) {
        int d = tid + j * 256;
        float y = ((v[j] - mu) * rstd * ln_s[d] + ln_b[d]) * mk;
        atomicAdd(&out[orow + d], y);
    }
}

// ---------------------------------------------------------------------------
// Final in-place LN over each [768] row of out.
__global__ __launch_bounds__(256) void final_ln_k(
    float* __restrict__ out, const float* __restrict__ ln_s,
    const float* __restrict__ ln_b)
{
    __shared__ float sm[8];
    int tid = threadIdx.x;
    float* row = out + (long)blockIdx.x * Dq;
    float v[3];
    float s = 0.f, ss = 0.f;
    #pragma unroll
    for (int j = 0; j < 3; ++j) {
        v[j] = row[tid + j * 256];
        s += v[j]; ss += v[j] * v[j];
    }
    block_reduce2(s, ss, sm);
    float mu = s * (1.0f / Dq);
    float var = ss * (1.0f / Dq) - mu * mu;
    float rstd = rsqrtf(var + 1e-12f);
    #pragma unroll
    for (int j = 0; j < 3; ++j) {
        int d = tid + j * 256;
        row[d] = (v[j] - mu) * rstd * ln_s[d] + ln_b[d];
    }
}

// ---------------------------------------------------------------------------
extern "C" void kernel_launch(void* const* d_in, const int* in_sizes, int n_in,
                              void* d_out, int out_size, void* d_ws, size_t ws_size,
                              hipStream_t stream) {
    const float* enc    = (const float*)d_in[0];
    const float* rv     = (const float*)d_in[1];
    const float* scores = (const float*)d_in[2];
    const int*   bpos   = (const int*)d_in[3];
    const int*   spos   = (const int*)d_in[4];
    const int*   epos   = (const int*)d_in[5];
    const float* mask   = (const float*)d_in[6];
    const float* vp_w   = (const float*)d_in[7];
    const float* vp_b   = (const float*)d_in[8];
    const float* cm_w   = (const float*)d_in[9];
    const float* cm_b   = (const float*)d_in[10];
    const float* cd_w   = (const float*)d_in[11];
    const float* cd_b   = (const float*)d_in[12];
    const float* ac_w1  = (const float*)d_in[13];
    const float* ac_b1  = (const float*)d_in[14];
    const float* ac_w2  = (const float*)d_in[15];
    const float* ac_b2  = (const float*)d_in[16];
    const float* ac_ln_s = (const float*)d_in[17];
    const float* ac_ln_b = (const float*)d_in[18];
    const float* pl_w1  = (const float*)d_in[19];
    const float* pl_b1  = (const float*)d_in[20];
    const float* pl_w2  = (const float*)d_in[21];
    const float* pl_b2  = (const float*)d_in[22];
    const float* pl_ln_s = (const float*)d_in[23];
    const float* pl_ln_b = (const float*)d_in[24];
    const float* ln_s   = (const float*)d_in[25];
    const float* ln_b   = (const float*)d_in[26];
    float* out = (float*)d_out;

    // workspace layout (bytes), ~224 MB of the confirmed 256 MiB
    char* wsb = (char*)d_ws;
    unsigned short* wt_cm = (unsigned short*)wsb; wsb += (size_t)1024 * 256 * 2;
    unsigned short* wt_cd = (unsigned short*)wsb; wsb += (size_t)768 * 1024 * 2;
    unsigned short* wt_a1 = (unsigned short*)wsb; wsb += (size_t)1024 * 768 * 2;
    unsigned short* wt_a2 = (unsigned short*)wsb; wsb += (size_t)768 * 1024 * 2;
    unsigned short* wt_p1 = (unsigned short*)wsb; wsb += (size_t)1024 * 768 * 2;
    unsigned short* wt_p2 = (unsigned short*)wsb; wsb += (size_t)768 * 1024 * 2;
    unsigned short* wt_vp = (unsigned short*)wsb; wsb += (size_t)128 * 1536 * 2;
    unsigned short* pmvb  = (unsigned short*)wsb; wsb += (size_t)Mq * Rq * 2;
    unsigned short* rvb   = (unsigned short*)wsb; wsb += (size_t)NROWS * Rq * 2;
    unsigned short* catenc = (unsigned short*)wsb; wsb += (size_t)Mq * 1536 * 2;
    unsigned short* hb    = (unsigned short*)wsb; wsb += (size_t)CH * Hq * 2;
    unsigned short* tb    = (unsigned short*)wsb; wsb += (size_t)CH * Dq * 2;
    unsigned short* cvb   = (unsigned short*)wsb; wsb += (size_t)CH * Dq * 2;
    float* partial = (float*)wsb; wsb += (size_t)(CH / Kq) * 4 * Dq * 4;
    float* pooledf = (float*)wsb; wsb += (size_t)Mq * Dq * 4;
    unsigned short* pooledb = (unsigned short*)wsb; wsb += (size_t)Mq * Dq * 2;
    float* puf     = (float*)wsb; wsb += (size_t)Mq * Dq * 4;

    // out = encoded_input (base for scatter-add)
    hipMemcpyAsync(out, enc, (size_t)Bq * Tq * Dq * sizeof(float),
                   hipMemcpyDeviceToDevice, stream);

    // weights -> bf16 transposed [N][K]; rv -> bf16
    wtrans_k<<<dim3(1024 / 32, 256 / 32), 256, 0, stream>>>(cm_w, wt_cm, 256, 1024);
    wtrans_k<<<dim3(768 / 32, 1024 / 32), 256, 0, stream>>>(cd_w, wt_cd, 1024, 768);
    wtrans_k<<<dim3(1024 / 32, 768 / 32), 256, 0, stream>>>(ac_w1, wt_a1, 768, 1024);
    wtrans_k<<<dim3(768 / 32, 1024 / 32), 256, 0, stream>>>(ac_w2, wt_a2, 1024, 768);
    wtrans_k<<<dim3(1024 / 32, 768 / 32), 256, 0, stream>>>(pl_w1, wt_p1, 768, 1024);
    wtrans_k<<<dim3(768 / 32, 1024 / 32), 256, 0, stream>>>(pl_w2, wt_p2, 1024, 768);
    wtrans_k<<<dim3(128 / 32, 1536 / 32), 256, 0, stream>>>(vp_w, wt_vp, 1536, 128);
    rv2bf_k<<<(NROWS * Rq) / (256 * 8), 256, 0, stream>>>(rv, rvb);

    // pmv = concat(start,end) @ vp_w + vp_b  as bf16 MFMA GEMM (128^2 kernel)
    gather_enc_k<<<Mq, 192, 0, stream>>>(enc, bpos, spos, epos, catenc);
    mgemm_k<0, 1, 0, 0><<<dim3(Mq / 128, 1), 256, 0, stream>>>(
        catenc, wt_vp, vp_b, pmvb, nullptr, 1536, Rq, nullptr, nullptr, 0);

    for (int c = 0; c < NCH; ++c) {
        int row_base = c * CH;
        int mbase = c * (CH / Kq);
        // h1 = gelu(concat(pmv,rv) @ cm_w + cm_b)   [CH,1024] bf16  (BN=256)
        mg8_k<1, 1, 0, 1, 4><<<dim3(CH / 256, Hq / 256), 512, 0, stream>>>(
            nullptr, wt_cm, cm_b, hb, nullptr, 2 * Rq, Hq, pmvb, rvb, row_base);
        // t = h1 @ cd_w + cd_b                      [CH,768] bf16  (BN=192)
        mg8_k<0, 1, 0, 0, 3><<<dim3(CH / 256, Dq / 192), 512, 0, stream>>>(
            hb, wt_cd, cd_b, tb, nullptr, Hq, Dq, nullptr, nullptr, 0);
        // h2 = gelu(t @ ac_w1 + ac_b1)              [CH,1024] bf16  (BN=256)
        mg8_k<1, 1, 0, 0, 4><<<dim3(CH / 256, Hq / 256), 512, 0, stream>>>(
            tb, wt_a1, ac_b1, hb, nullptr, Dq, Hq, nullptr, nullptr, 0);
        // cv = h2 @ ac_w2 + ac_b2 + t               [CH,768] bf16  (BN=192)
        mg8_k<0, 1, 1, 0, 3><<<dim3(CH / 256, Dq / 192), 512, 0, stream>>>(
            hb, wt_a2, ac_b2, cvb, tb, Hq, Dq, nullptr, nullptr, 0);
        // LN + score-weighted pool (split-k over 4 blocks/mention, then combine)
        ln_pool_part_k<<<(CH / Kq) * 4, 512, 0, stream>>>(
            cvb, scores, ac_ln_s, ac_ln_b, partial, mbase);
        ln_pool_comb_k<<<CH / Kq, 256, 0, stream>>>(partial, pooledf, pooledb, mbase);
    }

    // pooled MLP (M=2048 -> 128^2 kernel)
    mgemm_k<1, 1, 0, 0><<<dim3(Mq / 128, Hq / 128), 256, 0, stream>>>(
        pooledb, wt_p1, pl_b1, hb, nullptr, Dq, Hq, nullptr, nullptr, 0);
    mgemm_k<0, 0, 0, 0><<<dim3(Mq / 128, Dq / 128), 256, 0, stream>>>(
        hb, wt_p2, pl_b2, puf, nullptr, Hq, Dq, nullptr, nullptr, 0);

    // LN(pu + pooled) * mask, scatter-add into out
    ln_mask_scatter_k<<<Mq, 256, 0, stream>>>(puf, pooledf, pl_ln_s, pl_ln_b,
                                              mask, bpos, spos, out);

    // final LN over every row of out
    final_ln_k<<<Bq * Tq, 256, 0, stream>>>(out, ln_s, ln_b);
}